// Round 1
// baseline (3003.272 us; speedup 1.0000x reference)
//
#include <hip/hip_runtime.h>
#include <hip/hip_bf16.h>
#include <math.h>
#include <type_traits>

using bf16 = __hip_bfloat16;

static constexpr int NB  = 4;
static constexpr int SEQ = 1024;
static constexpr int DM  = 1024;
static constexpr int NH  = 16;
static constexpr int DHD = 64;
static constexpr int DFF = 4096;

__device__ __forceinline__ float u2f(unsigned short u) {
  return __uint_as_float(((unsigned int)u) << 16);
}

// ---------------------------------------------------------------------------
// Generic tiled SGEMM: C[M,N] = alpha * A[M,K] @ B[K,N]  (+bias)(+gelu)(+res)
// A: float or bf16. Output: float or bf16. 64x64 tile, BK=16, 256 thr, 4x4/thr
// ---------------------------------------------------------------------------
template <typename AT, typename OT, bool HASBIAS, bool HASRES, bool DOGELU>
__global__ __launch_bounds__(256) void sgemm_k(
    const AT* __restrict__ A, const float* __restrict__ Bm, OT* __restrict__ C,
    int M, int Nn, int K, float alpha,
    const float* __restrict__ bias, const float* __restrict__ res) {
  __shared__ float As[16][68];
  __shared__ float Bs[16][68];
  const int tid = threadIdx.x;
  const int tx = tid & 15, ty = tid >> 4;
  const int row0 = blockIdx.y << 6, col0 = blockIdx.x << 6;
  const int ar = tid >> 2, ak = (tid & 3) << 2;   // A: 64 rows x 16 k
  const int bk = tid >> 4, bc = (tid & 15) << 2;  // B: 16 k x 64 cols
  float acc[4][4] = {{0.f, 0.f, 0.f, 0.f}};
  const AT* aptr = A + (size_t)(row0 + ar) * K + ak;
  const float* bptr = Bm + (size_t)bk * Nn + col0 + bc;

  for (int k0 = 0; k0 < K; k0 += 16) {
    float4 av;
    if constexpr (std::is_same<AT, float>::value) {
      av = *reinterpret_cast<const float4*>(aptr + k0);
    } else {
      ushort4 u = *reinterpret_cast<const ushort4*>(aptr + k0);
      av.x = u2f(u.x); av.y = u2f(u.y); av.z = u2f(u.z); av.w = u2f(u.w);
    }
    float4 bv = *reinterpret_cast<const float4*>(bptr + (size_t)k0 * Nn);
    As[ak + 0][ar] = av.x;
    As[ak + 1][ar] = av.y;
    As[ak + 2][ar] = av.z;
    As[ak + 3][ar] = av.w;
    *reinterpret_cast<float4*>(&Bs[bk][bc]) = bv;
    __syncthreads();
#pragma unroll
    for (int kk = 0; kk < 16; ++kk) {
      float4 a4 = *reinterpret_cast<const float4*>(&As[kk][ty << 2]);
      float4 b4 = *reinterpret_cast<const float4*>(&Bs[kk][tx << 2]);
      float a[4] = {a4.x, a4.y, a4.z, a4.w};
      float b[4] = {b4.x, b4.y, b4.z, b4.w};
#pragma unroll
      for (int i = 0; i < 4; ++i)
#pragma unroll
        for (int j = 0; j < 4; ++j) acc[i][j] = fmaf(a[i], b[j], acc[i][j]);
    }
    __syncthreads();
  }

#pragma unroll
  for (int i = 0; i < 4; ++i) {
    const int r = row0 + (ty << 2) + i;
    const size_t rowoff = (size_t)r * Nn;
#pragma unroll
    for (int j = 0; j < 4; ++j) {
      const int c = col0 + (tx << 2) + j;
      float v = acc[i][j] * alpha;
      if constexpr (HASBIAS) v += bias[c];
      if constexpr (DOGELU) {
        const float x = v;
        v = 0.5f * x * (1.f + tanhf(0.7978845608f * (x + 0.044715f * x * x * x)));
      }
      if constexpr (HASRES) v += res[rowoff + c];
      if constexpr (std::is_same<OT, float>::value)
        C[rowoff + c] = v;
      else
        C[rowoff + c] = __float2bfloat16(v);
    }
  }
}

// ---------------------------------------------------------------------------
// LayerNorm over rows of length 1024
// ---------------------------------------------------------------------------
__global__ __launch_bounds__(256) void ln_k(const float* __restrict__ in,
                                            const float* __restrict__ g,
                                            const float* __restrict__ b,
                                            float* __restrict__ out) {
  const int tid = threadIdx.x;
  const int c = tid << 2;
  const size_t base = (size_t)blockIdx.x * DM;
  float4 x = *reinterpret_cast<const float4*>(in + base + c);
  float s = x.x + x.y + x.z + x.w;
  float ss = x.x * x.x + x.y * x.y + x.z * x.z + x.w * x.w;
#pragma unroll
  for (int m = 1; m < 64; m <<= 1) {
    s += __shfl_xor(s, m, 64);
    ss += __shfl_xor(ss, m, 64);
  }
  __shared__ float ls[4], lss[4];
  if ((tid & 63) == 0) { ls[tid >> 6] = s; lss[tid >> 6] = ss; }
  __syncthreads();
  s = (ls[0] + ls[1]) + (ls[2] + ls[3]);
  ss = (lss[0] + lss[1]) + (lss[2] + lss[3]);
  const float mu = s * (1.f / DM);
  const float var = ss * (1.f / DM) - mu * mu;
  const float rstd = rsqrtf(var + 1e-5f);
  float4 g4 = *reinterpret_cast<const float4*>(g + c);
  float4 b4 = *reinterpret_cast<const float4*>(b + c);
  float4 o;
  o.x = (x.x - mu) * rstd * g4.x + b4.x;
  o.y = (x.y - mu) * rstd * g4.y + b4.y;
  o.z = (x.z - mu) * rstd * g4.z + b4.z;
  o.w = (x.w - mu) * rstd * g4.w + b4.w;
  *reinterpret_cast<float4*>(out + base + c) = o;
}

// ---------------------------------------------------------------------------
// hs2 = t5norm(shift_right_63(cca) + hs) * w     (rows of 1024)
// ---------------------------------------------------------------------------
__global__ __launch_bounds__(256) void t5_k(const float* __restrict__ cca,
                                            const float* __restrict__ hs,
                                            const float* __restrict__ w,
                                            float* __restrict__ out) {
  const int tid = threadIdx.x;
  const int row = blockIdx.x;
  const int t = row & (SEQ - 1);
  const int c = tid << 2;
  const size_t base = (size_t)row * DM;
  float4 x = *reinterpret_cast<const float4*>(hs + base + c);
  if (t >= 63) {
    float4 cc = *reinterpret_cast<const float4*>(cca + base - (size_t)63 * DM + c);
    x.x += cc.x; x.y += cc.y; x.z += cc.z; x.w += cc.w;
  }
  float ss = x.x * x.x + x.y * x.y + x.z * x.z + x.w * x.w;
#pragma unroll
  for (int m = 1; m < 64; m <<= 1) ss += __shfl_xor(ss, m, 64);
  __shared__ float lss[4];
  if ((tid & 63) == 0) lss[tid >> 6] = ss;
  __syncthreads();
  ss = (lss[0] + lss[1]) + (lss[2] + lss[3]);
  const float rms = sqrtf(ss * (1.f / DM));
  const float inv = 1.f / fmaxf(rms, 1e-6f);
  float4 w4 = *reinterpret_cast<const float4*>(w + c);
  float4 o;
  o.x = x.x * inv * w4.x;
  o.y = x.y * inv * w4.y;
  o.z = x.z * inv * w4.z;
  o.w = x.w * inv * w4.w;
  *reinterpret_cast<float4*>(out + base + c) = o;
}

// ---------------------------------------------------------------------------
// xq[b,t,:] = hs[b,t+63,:] if t<=960 else 0     (float4 elementwise)
// ---------------------------------------------------------------------------
__global__ __launch_bounds__(256) void xq_k(const float* __restrict__ hs,
                                            float* __restrict__ xq) {
  const int i = blockIdx.x * 256 + threadIdx.x;  // float4 index, 1M total
  const int row = i >> 8;                        // 256 float4 per row
  const int t = row & (SEQ - 1);
  float4 v = make_float4(0.f, 0.f, 0.f, 0.f);
  if (t < SEQ - 63) v = reinterpret_cast<const float4*>(hs)[i + 63 * 256];
  reinterpret_cast<float4*>(xq)[i] = v;
}

// ---------------------------------------------------------------------------
// rotary on q: only row i==0 of each chunk (freqs = q_pos_emb[63,:]); in-place
// q layout: [64 chunks][64 rows][16 h][64 c]; one block per chunk
// ---------------------------------------------------------------------------
__global__ __launch_bounds__(256) void rotq_k(float* __restrict__ q,
                                              const float* __restrict__ qpe) {
  __shared__ float rb[DM];
  const size_t base = (size_t)blockIdx.x * 64 * DM;  // row (chunk, i=0)
  const int e = threadIdx.x << 2;
  float4 v = *reinterpret_cast<const float4*>(q + base + e);
  *reinterpret_cast<float4*>(&rb[e]) = v;
  __syncthreads();
  float ov[4];
#pragma unroll
  for (int u = 0; u < 4; ++u) {
    const int ee = e + u;
    const int cc = ee & 63;
    const float f = qpe[63 * 64 + cc];
    const float t1 = rb[ee];
    const float part = (cc < 32) ? -rb[ee + 32] : rb[ee - 32];
    ov[u] = t1 * cosf(f) + part * sinf(f);
  }
  float4 o = make_float4(ov[0], ov[1], ov[2], ov[3]);
  *reinterpret_cast<float4*>(q + base + e) = o;
}

// ---------------------------------------------------------------------------
// rotary on kk (bf16, in-place): row rr = bk*256 + j, freqs = k_pos_emb[j&127]
// ---------------------------------------------------------------------------
__global__ __launch_bounds__(256) void rotk_k(bf16* __restrict__ kkb,
                                              const float* __restrict__ kpe) {
  const int rr = blockIdx.x;
  const int j = rr & 255;
  const float* fr = kpe + (size_t)(j & 127) * 64;
  __shared__ float rb[DM];
  const size_t base = (size_t)rr * DM;
  const int e = threadIdx.x << 2;
  ushort4 u = *reinterpret_cast<const ushort4*>(kkb + base + e);
  rb[e + 0] = u2f(u.x);
  rb[e + 1] = u2f(u.y);
  rb[e + 2] = u2f(u.z);
  rb[e + 3] = u2f(u.w);
  __syncthreads();
#pragma unroll
  for (int uu = 0; uu < 4; ++uu) {
    const int ee = e + uu;
    const int cc = ee & 63;
    const float f = fr[cc];
    const float t1 = rb[ee];
    const float part = (cc < 32) ? -rb[ee + 32] : rb[ee - 32];
    kkb[base + ee] = __float2bfloat16(t1 * cosf(f) + part * sinf(f));
  }
}

// ---------------------------------------------------------------------------
// causal self-attention, one block per (qtile, h, b); 64x64 tiles, online SM
// q,k,v,o layout: [B, N, H*DH] merged
// ---------------------------------------------------------------------------
__global__ __launch_bounds__(256) void attn_self_k(const float* __restrict__ q,
                                                   const float* __restrict__ k,
                                                   const float* __restrict__ v,
                                                   float* __restrict__ o) {
  const int qt = blockIdx.x, h = blockIdx.y, b = blockIdx.z;
  __shared__ float qsT[64][68];  // [c][row]
  __shared__ float kps[64][68];  // ksT [c][key] then P [row][key]
  __shared__ float vs[64][68];   // [key][c]
  const int tid = threadIdx.x;
  const int tx = tid & 15, ty = tid >> 4;
  const size_t bhbase = (size_t)b * SEQ * DM + (size_t)h * DHD;

#pragma unroll
  for (int rp = 0; rp < 4; ++rp) {
    const int fi = tid + rp * 256;
    const int r = fi >> 4, c4 = (fi & 15) << 2;
    float4 qv = *reinterpret_cast<const float4*>(q + bhbase + (size_t)(qt * 64 + r) * DM + c4);
    qsT[c4 + 0][r] = qv.x;
    qsT[c4 + 1][r] = qv.y;
    qsT[c4 + 2][r] = qv.z;
    qsT[c4 + 3][r] = qv.w;
  }
  float mrun[4], lrun[4], accO[4][4];
#pragma unroll
  for (int i = 0; i < 4; ++i) {
    mrun[i] = -1e30f;
    lrun[i] = 0.f;
#pragma unroll
    for (int j = 0; j < 4; ++j) accO[i][j] = 0.f;
  }

  for (int kt = 0; kt <= qt; ++kt) {
    __syncthreads();  // prev-iter reads done; also publishes qsT on iter 0
#pragma unroll
    for (int rp = 0; rp < 4; ++rp) {
      const int fi = tid + rp * 256;
      const int r = fi >> 4, c4 = (fi & 15) << 2;
      const size_t g = bhbase + (size_t)(kt * 64 + r) * DM + c4;
      float4 kv = *reinterpret_cast<const float4*>(k + g);
      kps[c4 + 0][r] = kv.x;
      kps[c4 + 1][r] = kv.y;
      kps[c4 + 2][r] = kv.z;
      kps[c4 + 3][r] = kv.w;
      float4 v4 = *reinterpret_cast<const float4*>(v + g);
      *reinterpret_cast<float4*>(&vs[r][c4]) = v4;
    }
    __syncthreads();

    float s[4][4] = {{0.f, 0.f, 0.f, 0.f}};
#pragma unroll 8
    for (int c = 0; c < 64; ++c) {
      float4 a4 = *reinterpret_cast<const float4*>(&qsT[c][ty << 2]);
      float4 b4 = *reinterpret_cast<const float4*>(&kps[c][tx << 2]);
      float a[4] = {a4.x, a4.y, a4.z, a4.w};
      float bb[4] = {b4.x, b4.y, b4.z, b4.w};
#pragma unroll
      for (int i = 0; i < 4; ++i)
#pragma unroll
        for (int j = 0; j < 4; ++j) s[i][j] = fmaf(a[i], bb[j], s[i][j]);
    }
    if (kt == qt) {
#pragma unroll
      for (int i = 0; i < 4; ++i)
#pragma unroll
        for (int j = 0; j < 4; ++j)
          if (((tx << 2) + j) > ((ty << 2) + i)) s[i][j] = -1e30f;
    }
#pragma unroll
    for (int i = 0; i < 4; ++i) {
      float mt = fmaxf(fmaxf(s[i][0], s[i][1]), fmaxf(s[i][2], s[i][3]));
      mt = fmaxf(mt, __shfl_xor(mt, 1, 16));
      mt = fmaxf(mt, __shfl_xor(mt, 2, 16));
      mt = fmaxf(mt, __shfl_xor(mt, 4, 16));
      mt = fmaxf(mt, __shfl_xor(mt, 8, 16));
      const float nm = fmaxf(mrun[i], mt);
      const float f = __expf(mrun[i] - nm);
      mrun[i] = nm;
      float rs = 0.f;
#pragma unroll
      for (int j = 0; j < 4; ++j) {
        s[i][j] = __expf(s[i][j] - nm);
        rs += s[i][j];
      }
      rs += __shfl_xor(rs, 1, 16);
      rs += __shfl_xor(rs, 2, 16);
      rs += __shfl_xor(rs, 4, 16);
      rs += __shfl_xor(rs, 8, 16);
      lrun[i] = lrun[i] * f + rs;
#pragma unroll
      for (int j = 0; j < 4; ++j) accO[i][j] *= f;
    }
    __syncthreads();  // done reading kps as ksT
#pragma unroll
    for (int i = 0; i < 4; ++i)
#pragma unroll
      for (int j = 0; j < 4; ++j) kps[(ty << 2) + i][(tx << 2) + j] = s[i][j];
    __syncthreads();
#pragma unroll 8
    for (int kx = 0; kx < 64; ++kx) {
      float4 v4 = *reinterpret_cast<const float4*>(&vs[kx][tx << 2]);
      const float p0 = kps[(ty << 2) + 0][kx];
      const float p1 = kps[(ty << 2) + 1][kx];
      const float p2 = kps[(ty << 2) + 2][kx];
      const float p3 = kps[(ty << 2) + 3][kx];
      accO[0][0] += p0 * v4.x; accO[0][1] += p0 * v4.y; accO[0][2] += p0 * v4.z; accO[0][3] += p0 * v4.w;
      accO[1][0] += p1 * v4.x; accO[1][1] += p1 * v4.y; accO[1][2] += p1 * v4.z; accO[1][3] += p1 * v4.w;
      accO[2][0] += p2 * v4.x; accO[2][1] += p2 * v4.y; accO[2][2] += p2 * v4.z; accO[2][3] += p2 * v4.w;
      accO[3][0] += p3 * v4.x; accO[3][1] += p3 * v4.y; accO[3][2] += p3 * v4.z; accO[3][3] += p3 * v4.w;
    }
  }
#pragma unroll
  for (int i = 0; i < 4; ++i) {
    const float inv = 1.f / lrun[i];
    float4 ov = make_float4(accO[i][0] * inv, accO[i][1] * inv, accO[i][2] * inv, accO[i][3] * inv);
    *reinterpret_cast<float4*>(o + bhbase + (size_t)(qt * 64 + (ty << 2) + i) * DM + (tx << 2)) = ov;
  }
}

// ---------------------------------------------------------------------------
// chunked cross-attention: 257 keys (null + 256 retrieved), no mask
// one block per (h, bk). q,o: [64bk, 64, H*DH] f32; kk,vv: [64bk, 256, H*DH] bf16
// ---------------------------------------------------------------------------
__global__ __launch_bounds__(256) void attn_cca_k(
    const float* __restrict__ q, const bf16* __restrict__ kkb,
    const bf16* __restrict__ vvb, const float* __restrict__ nullk,
    const float* __restrict__ nullv, float* __restrict__ o) {
  const int h = blockIdx.y, bk = blockIdx.z;
  __shared__ float qsT[64][68];
  __shared__ float kps[64][68];
  __shared__ float vs[64][68];
  const int tid = threadIdx.x;
  const int tx = tid & 15, ty = tid >> 4;
  const size_t qbase = (size_t)bk * 64 * DM + (size_t)h * DHD;

#pragma unroll
  for (int rp = 0; rp < 4; ++rp) {
    const int fi = tid + rp * 256;
    const int r = fi >> 4, c4 = (fi & 15) << 2;
    float4 qv = *reinterpret_cast<const float4*>(q + qbase + (size_t)r * DM + c4);
    qsT[c4 + 0][r] = qv.x;
    qsT[c4 + 1][r] = qv.y;
    qsT[c4 + 2][r] = qv.z;
    qsT[c4 + 3][r] = qv.w;
  }
  float mrun[4], lrun[4], accO[4][4];
#pragma unroll
  for (int i = 0; i < 4; ++i) {
    mrun[i] = -1e30f;
    lrun[i] = 0.f;
#pragma unroll
    for (int j = 0; j < 4; ++j) accO[i][j] = 0.f;
  }

  for (int kt = 0; kt < 5; ++kt) {
    __syncthreads();
#pragma unroll
    for (int rp = 0; rp < 4; ++rp) {
      const int fi = tid + rp * 256;
      const int r = fi >> 4, c4 = (fi & 15) << 2;
      const int kj = kt * 64 + r;
      float4 kv = make_float4(0.f, 0.f, 0.f, 0.f);
      float4 v4 = make_float4(0.f, 0.f, 0.f, 0.f);
      if (kj < 257) {
        if (kj == 0) {
          kv = *reinterpret_cast<const float4*>(nullk + h * DHD + c4);
          v4 = *reinterpret_cast<const float4*>(nullv + h * DHD + c4);
        } else {
          const size_t g = ((size_t)bk * 256 + (kj - 1)) * DM + h * DHD + c4;
          ushort4 ku = *reinterpret_cast<const ushort4*>(kkb + g);
          ushort4 vu = *reinterpret_cast<const ushort4*>(vvb + g);
          kv = make_float4(u2f(ku.x), u2f(ku.y), u2f(ku.z), u2f(ku.w));
          v4 = make_float4(u2f(vu.x), u2f(vu.y), u2f(vu.z), u2f(vu.w));
        }
      }
      kps[c4 + 0][r] = kv.x;
      kps[c4 + 1][r] = kv.y;
      kps[c4 + 2][r] = kv.z;
      kps[c4 + 3][r] = kv.w;
      *reinterpret_cast<float4*>(&vs[r][c4]) = v4;
    }
    __syncthreads();

    float s[4][4] = {{0.f, 0.f, 0.f, 0.f}};
#pragma unroll 8
    for (int c = 0; c < 64; ++c) {
      float4 a4 = *reinterpret_cast<const float4*>(&qsT[c][ty << 2]);
      float4 b4 = *reinterpret_cast<const float4*>(&kps[c][tx << 2]);
      float a[4] = {a4.x, a4.y, a4.z, a4.w};
      float bb[4] = {b4.x, b4.y, b4.z, b4.w};
#pragma unroll
      for (int i = 0; i < 4; ++i)
#pragma unroll
        for (int j = 0; j < 4; ++j) s[i][j] = fmaf(a[i], bb[j], s[i][j]);
    }
    if (kt == 4) {  // only key 256 (local 0) is valid in the last tile
#pragma unroll
      for (int i = 0; i < 4; ++i)
#pragma unroll
        for (int j = 0; j < 4; ++j)
          if (((tx << 2) + j) >= 1) s[i][j] = -1e30f;
    }
#pragma unroll
    for (int i = 0; i < 4; ++i) {
      float mt = fmaxf(fmaxf(s[i][0], s[i][1]), fmaxf(s[i][2], s[i][3]));
      mt = fmaxf(mt, __shfl_xor(mt, 1, 16));
      mt = fmaxf(mt, __shfl_xor(mt, 2, 16));
      mt = fmaxf(mt, __shfl_xor(mt, 4, 16));
      mt = fmaxf(mt, __shfl_xor(mt, 8, 16));
      const float nm = fmaxf(mrun[i], mt);
      const float f = __expf(mrun[i] - nm);
      mrun[i] = nm;
      float rs = 0.f;
#pragma unroll
      for (int j = 0; j < 4; ++j) {
        s[i][j] = __expf(s[i][j] - nm);
        rs += s[i][j];
      }
      rs += __shfl_xor(rs, 1, 16);
      rs += __shfl_xor(rs, 2, 16);
      rs += __shfl_xor(rs, 4, 16);
      rs += __shfl_xor(rs, 8, 16);
      lrun[i] = lrun[i] * f + rs;
#pragma unroll
      for (int j = 0; j < 4; ++j) accO[i][j] *= f;
    }
    __syncthreads();
#pragma unroll
    for (int i = 0; i < 4; ++i)
#pragma unroll
      for (int j = 0; j < 4; ++j) kps[(ty << 2) + i][(tx << 2) + j] = s[i][j];
    __syncthreads();
#pragma unroll 8
    for (int kx = 0; kx < 64; ++kx) {
      float4 v4 = *reinterpret_cast<const float4*>(&vs[kx][tx << 2]);
      const float p0 = kps[(ty << 2) + 0][kx];
      const float p1 = kps[(ty << 2) + 1][kx];
      const float p2 = kps[(ty << 2) + 2][kx];
      const float p3 = kps[(ty << 2) + 3][kx];
      accO[0][0] += p0 * v4.x; accO[0][1] += p0 * v4.y; accO[0][2] += p0 * v4.z; accO[0][3] += p0 * v4.w;
      accO[1][0] += p1 * v4.x; accO[1][1] += p1 * v4.y; accO[1][2] += p1 * v4.z; accO[1][3] += p1 * v4.w;
      accO[2][0] += p2 * v4.x; accO[2][1] += p2 * v4.y; accO[2][2] += p2 * v4.z; accO[2][3] += p2 * v4.w;
      accO[3][0] += p3 * v4.x; accO[3][1] += p3 * v4.y; accO[3][2] += p3 * v4.z; accO[3][3] += p3 * v4.w;
    }
  }
#pragma unroll
  for (int i = 0; i < 4; ++i) {
    const float inv = 1.f / lrun[i];
    float4 ov = make_float4(accO[i][0] * inv, accO[i][1] * inv, accO[i][2] * inv, accO[i][3] * inv);
    *reinterpret_cast<float4*>(o + qbase + (size_t)((ty << 2) + i) * DM + (tx << 2)) = ov;
  }
}

// ---------------------------------------------------------------------------
extern "C" void kernel_launch(void* const* d_in, const int* in_sizes, int n_in,
                              void* d_out, int out_size, void* d_ws, size_t ws_size,
                              hipStream_t stream) {
  const float* hidden    = (const float*)d_in[0];
  const float* retrieval = (const float*)d_in[1];
  const float* q_pos     = (const float*)d_in[2];
  const float* k_pos     = (const float*)d_in[3];
  const float* ln1_g     = (const float*)d_in[4];
  const float* ln1_b     = (const float*)d_in[5];
  const float* Wq_s      = (const float*)d_in[6];
  const float* Wk_s      = (const float*)d_in[7];
  const float* Wv_s      = (const float*)d_in[8];
  const float* Wo_s      = (const float*)d_in[9];
  const float* bo_s      = (const float*)d_in[10];
  const float* ln2_g     = (const float*)d_in[11];
  const float* ln2_b     = (const float*)d_in[12];
  const float* Wq_c      = (const float*)d_in[13];
  const float* Wk_c      = (const float*)d_in[14];
  const float* Wv_c      = (const float*)d_in[15];
  const float* Wo_c      = (const float*)d_in[16];
  const float* bo_c      = (const float*)d_in[17];
  const float* null_k    = (const float*)d_in[18];
  const float* null_v    = (const float*)d_in[19];
  const float* post_w    = (const float*)d_in[20];
  const float* W1        = (const float*)d_in[21];
  const float* b1        = (const float*)d_in[22];
  const float* W2        = (const float*)d_in[23];
  const float* b2        = (const float*)d_in[24];
  float* out = (float*)d_out;

  constexpr size_t SLOT = (size_t)4 * 1024 * 1024;  // floats per 16MB slot
  float* wsf = (float*)d_ws;
  float* s0 = wsf + 0 * SLOT;
  float* s1 = wsf + 1 * SLOT;
  float* s2 = wsf + 2 * SLOT;
  float* s3 = wsf + 3 * SLOT;
  float* s4 = wsf + 4 * SLOT;
  float* s5 = wsf + 5 * SLOT;  // hs (residual) — persists
  bf16* kkb = (bf16*)(wsf + 6 * SLOT);         // 16384x1024 bf16 = 32MB
  bf16* vvb = kkb + (size_t)16384 * 1024;      // 32MB
  bf16* ff1b = kkb;                            // alias (kk dead by then)

  const dim3 blk(256);
  const dim3 g64x1k(1024 / 64, 4096 / 64);     // M=4096, N=1024
  const dim3 g64x16k(1024 / 64, 16384 / 64);   // M=16384, N=1024
  const dim3 gff1(4096 / 64, 4096 / 64);       // M=4096, N=4096

  // 1. x = LN1(hidden)
  ln_k<<<dim3(4096), blk, 0, stream>>>(hidden, ln1_g, ln1_b, s0);
  // 2-4. q,k,v projections (q scaled by 1/8)
  sgemm_k<float, float, false, false, false><<<g64x1k, blk, 0, stream>>>(
      s0, Wq_s, s1, 4096, 1024, 1024, 0.125f, nullptr, nullptr);
  sgemm_k<float, float, false, false, false><<<g64x1k, blk, 0, stream>>>(
      s0, Wk_s, s2, 4096, 1024, 1024, 1.f, nullptr, nullptr);
  sgemm_k<float, float, false, false, false><<<g64x1k, blk, 0, stream>>>(
      s0, Wv_s, s3, 4096, 1024, 1024, 1.f, nullptr, nullptr);
  // 5. causal self-attention -> s4
  attn_self_k<<<dim3(16, 16, 4), blk, 0, stream>>>(s1, s2, s3, s4);
  // 6. o = attn @ Wo_s + bo_s + hidden  -> s0
  sgemm_k<float, float, true, true, false><<<g64x1k, blk, 0, stream>>>(
      s4, Wo_s, s0, 4096, 1024, 1024, 1.f, bo_s, hidden);
  // 7. hs = LN2(s0) -> s5 (residual)
  ln_k<<<dim3(4096), blk, 0, stream>>>(s0, ln2_g, ln2_b, s5);
  // 8. xq = shift(hs) -> s1
  xq_k<<<dim3(4096), blk, 0, stream>>>(s5, s1);
  // 9. q_c = (xq @ Wq_c) * 1/8 -> s2, then rotary (row 0 of each chunk)
  sgemm_k<float, float, false, false, false><<<g64x1k, blk, 0, stream>>>(
      s1, Wq_c, s2, 4096, 1024, 1024, 0.125f, nullptr, nullptr);
  rotq_k<<<dim3(64), blk, 0, stream>>>(s2, q_pos);
  // 10. kk = ctx @ Wk_c (bf16) + rotary; vv = ctx @ Wv_c (bf16)
  sgemm_k<float, bf16, false, false, false><<<g64x16k, blk, 0, stream>>>(
      retrieval, Wk_c, kkb, 16384, 1024, 1024, 1.f, nullptr, nullptr);
  rotk_k<<<dim3(16384), blk, 0, stream>>>(kkb, k_pos);
  sgemm_k<float, bf16, false, false, false><<<g64x16k, blk, 0, stream>>>(
      retrieval, Wv_c, vvb, 16384, 1024, 1024, 1.f, nullptr, nullptr);
  // 11. cross attention -> s3
  attn_cca_k<<<dim3(1, 16, 64), blk, 0, stream>>>(s2, kkb, vvb, null_k, null_v, s3);
  // 12. cca proj -> s4 (unshifted, xq-space)
  sgemm_k<float, float, true, false, false><<<g64x1k, blk, 0, stream>>>(
      s3, Wo_c, s4, 4096, 1024, 1024, 1.f, bo_c, nullptr);
  // 13. hs2 = t5norm(shift(s4) + hs) -> s0
  t5_k<<<dim3(4096), blk, 0, stream>>>(s4, s5, post_w, s0);
  // 14. ff1 = gelu(hs2 @ W1 + b1) -> bf16
  sgemm_k<float, bf16, true, false, true><<<gff1, blk, 0, stream>>>(
      s0, W1, ff1b, 4096, 4096, 1024, 1.f, b1, nullptr);
  // 15. out = ff1 @ W2 + b2 + hs
  sgemm_k<bf16, float, true, true, false><<<g64x1k, blk, 0, stream>>>(
      ff1b, W2, out, 4096, 1024, 4096, 1.f, b2, s5);
}

// Round 2
// 947.564 us; speedup vs baseline: 3.1695x; 3.1695x over previous
//
#include <hip/hip_runtime.h>
#include <hip/hip_bf16.h>
#include <math.h>

using u16 = unsigned short;

static constexpr int SEQ = 1024;
static constexpr int DM  = 1024;
static constexpr int DHD = 64;

typedef __bf16 bfv8 __attribute__((ext_vector_type(8)));
typedef float  f32x4 __attribute__((ext_vector_type(4)));

__device__ __forceinline__ float u2f(u16 u) {
  return __uint_as_float(((unsigned int)u) << 16);
}
__device__ __forceinline__ u16 f2b(float x) {
  __hip_bfloat16 h = __float2bfloat16(x);
  return *reinterpret_cast<u16*>(&h);
}
__device__ __forceinline__ void gload16(const u16* g, u16* l) {
  __builtin_amdgcn_global_load_lds(
      (const __attribute__((address_space(1))) unsigned int*)g,
      (__attribute__((address_space(3))) unsigned int*)l, 16, 0, 0);
}

// ---------------------------------------------------------------------------
// MFMA bf16 GEMM: C[M,N] = alpha*A[M,K]@Bt[N,K]^T (+bias)(+gelu)(+res)
// 128x128 tile, BK=64, 4 waves, 16x16x32 MFMA, global_load_lds staging (m97)
// ---------------------------------------------------------------------------
template <int OT /*0=f32,1=bf16*/, bool HASBIAS, bool HASRES, bool DOGELU>
__global__ __launch_bounds__(256) void mgemm_k(
    const u16* __restrict__ A, const u16* __restrict__ Bt, void* __restrict__ C,
    int M, int N, int K, float alpha,
    const float* __restrict__ bias, const float* __restrict__ res) {
  __shared__ u16 As[128 * 64];
  __shared__ u16 Bs[128 * 64];
  const int tid = threadIdx.x;
  const int w = tid >> 6, lane = tid & 63;
  const int wr = w >> 1, wc = w & 1;
  const int row0 = blockIdx.y << 7, col0 = blockIdx.x << 7;
  f32x4 acc[4][4] = {};

  const int c0 = (w << 2) * 64 + lane;  // base chunk id for issue i=0
  for (int k0 = 0; k0 < K; k0 += 64) {
#pragma unroll
    for (int i = 0; i < 4; ++i) {
      const int c = c0 + (i << 6);
      const int r = c >> 3, cb = (c & 7) << 3;
      gload16(A + (size_t)(row0 + r) * K + k0 + cb, &As[((w << 2) + i) << 9]);
      gload16(Bt + (size_t)(col0 + r) * K + k0 + cb, &Bs[((w << 2) + i) << 9]);
    }
    __syncthreads();
#pragma unroll
    for (int kk = 0; kk < 2; ++kk) {
      bfv8 af[4], bfr[4];
#pragma unroll
      for (int m = 0; m < 4; ++m)
        af[m] = *reinterpret_cast<const bfv8*>(
            &As[((wr << 6) + (m << 4) + (lane & 15)) * 64 + (kk << 5) + ((lane >> 4) << 3)]);
#pragma unroll
      for (int n = 0; n < 4; ++n)
        bfr[n] = *reinterpret_cast<const bfv8*>(
            &Bs[((wc << 6) + (n << 4) + (lane & 15)) * 64 + (kk << 5) + ((lane >> 4) << 3)]);
#pragma unroll
      for (int m = 0; m < 4; ++m)
#pragma unroll
        for (int n = 0; n < 4; ++n)
          acc[m][n] = __builtin_amdgcn_mfma_f32_16x16x32_bf16(af[m], bfr[n], acc[m][n], 0, 0, 0);
    }
    __syncthreads();
  }

  const int lr = (lane >> 4) << 2;
  const int lc = lane & 15;
#pragma unroll
  for (int m = 0; m < 4; ++m) {
#pragma unroll
    for (int n = 0; n < 4; ++n) {
#pragma unroll
      for (int r = 0; r < 4; ++r) {
        const int gr = row0 + (wr << 6) + (m << 4) + lr + r;
        const int gc = col0 + (wc << 6) + (n << 4) + lc;
        float v = acc[m][n][r] * alpha;
        if constexpr (HASBIAS) v += bias[gc];
        if constexpr (DOGELU) {
          const float x = v;
          v = 0.5f * x * (1.f + tanhf(0.7978845608f * (x + 0.044715f * x * x * x)));
        }
        if constexpr (HASRES) v += res[(size_t)gr * N + gc];
        if constexpr (OT == 0)
          ((float*)C)[(size_t)gr * N + gc] = v;
        else
          ((u16*)C)[(size_t)gr * N + gc] = f2b(v);
      }
    }
  }
}

// ---------------------------------------------------------------------------
// weight transpose+cast: in f32 [K,N] -> out bf16 [N,K]
// ---------------------------------------------------------------------------
__global__ __launch_bounds__(256) void wtrans_k(const float* __restrict__ in,
                                                u16* __restrict__ out, int K, int N) {
  __shared__ float t[32][33];
  const int tx = threadIdx.x & 31, ty = threadIdx.x >> 5;
  const int r0 = blockIdx.y << 5, c0 = blockIdx.x << 5;
#pragma unroll
  for (int i = 0; i < 4; ++i)
    t[ty + 8 * i][tx] = in[(size_t)(r0 + ty + 8 * i) * N + c0 + tx];
  __syncthreads();
#pragma unroll
  for (int i = 0; i < 4; ++i)
    out[(size_t)(c0 + ty + 8 * i) * K + r0 + tx] = f2b(t[tx][ty + 8 * i]);
}

// flat f32 -> bf16 cast (one float4 per thread)
__global__ __launch_bounds__(256) void cast_k(const float* __restrict__ in,
                                              u16* __restrict__ out) {
  const int i = blockIdx.x * 256 + threadIdx.x;
  float4 v = reinterpret_cast<const float4*>(in)[i];
  ushort4 o = {f2b(v.x), f2b(v.y), f2b(v.z), f2b(v.w)};
  reinterpret_cast<ushort4*>(out)[i] = o;
}

// ---------------------------------------------------------------------------
// LayerNorm rows of 1024; f32 in, f32 or bf16 out
// ---------------------------------------------------------------------------
template <bool BF16OUT>
__global__ __launch_bounds__(256) void ln_k(const float* __restrict__ in,
                                            const float* __restrict__ g,
                                            const float* __restrict__ b,
                                            void* __restrict__ out) {
  const int tid = threadIdx.x;
  const int c = tid << 2;
  const size_t base = (size_t)blockIdx.x * DM;
  float4 x = *reinterpret_cast<const float4*>(in + base + c);
  float s = x.x + x.y + x.z + x.w;
  float ss = x.x * x.x + x.y * x.y + x.z * x.z + x.w * x.w;
#pragma unroll
  for (int m = 1; m < 64; m <<= 1) {
    s += __shfl_xor(s, m, 64);
    ss += __shfl_xor(ss, m, 64);
  }
  __shared__ float ls[4], lss[4];
  if ((tid & 63) == 0) { ls[tid >> 6] = s; lss[tid >> 6] = ss; }
  __syncthreads();
  s = (ls[0] + ls[1]) + (ls[2] + ls[3]);
  ss = (lss[0] + lss[1]) + (lss[2] + lss[3]);
  const float mu = s * (1.f / DM);
  const float var = ss * (1.f / DM) - mu * mu;
  const float rstd = rsqrtf(var + 1e-5f);
  float4 g4 = *reinterpret_cast<const float4*>(g + c);
  float4 b4 = *reinterpret_cast<const float4*>(b + c);
  float4 o;
  o.x = (x.x - mu) * rstd * g4.x + b4.x;
  o.y = (x.y - mu) * rstd * g4.y + b4.y;
  o.z = (x.z - mu) * rstd * g4.z + b4.z;
  o.w = (x.w - mu) * rstd * g4.w + b4.w;
  if constexpr (BF16OUT) {
    ushort4 u = {f2b(o.x), f2b(o.y), f2b(o.z), f2b(o.w)};
    *reinterpret_cast<ushort4*>((u16*)out + base + c) = u;
  } else {
    *reinterpret_cast<float4*>((float*)out + base + c) = o;
  }
}

// ---------------------------------------------------------------------------
// t5norm(shift_right_63(cca_bf16) + hs_f32) * w -> bf16
// ---------------------------------------------------------------------------
__global__ __launch_bounds__(256) void t5_k(const u16* __restrict__ cca,
                                            const float* __restrict__ hs,
                                            const float* __restrict__ w,
                                            u16* __restrict__ out) {
  const int tid = threadIdx.x;
  const int row = blockIdx.x;
  const int t = row & (SEQ - 1);
  const int c = tid << 2;
  const size_t base = (size_t)row * DM;
  float4 x = *reinterpret_cast<const float4*>(hs + base + c);
  if (t >= 63) {
    ushort4 cu = *reinterpret_cast<const ushort4*>(cca + base - (size_t)63 * DM + c);
    x.x += u2f(cu.x); x.y += u2f(cu.y); x.z += u2f(cu.z); x.w += u2f(cu.w);
  }
  float ss = x.x * x.x + x.y * x.y + x.z * x.z + x.w * x.w;
#pragma unroll
  for (int m = 1; m < 64; m <<= 1) ss += __shfl_xor(ss, m, 64);
  __shared__ float lss[4];
  if ((tid & 63) == 0) lss[tid >> 6] = ss;
  __syncthreads();
  ss = (lss[0] + lss[1]) + (lss[2] + lss[3]);
  const float rms = sqrtf(ss * (1.f / DM));
  const float inv = 1.f / fmaxf(rms, 1e-6f);
  float4 w4 = *reinterpret_cast<const float4*>(w + c);
  ushort4 o = {f2b(x.x * inv * w4.x), f2b(x.y * inv * w4.y),
               f2b(x.z * inv * w4.z), f2b(x.w * inv * w4.w)};
  *reinterpret_cast<ushort4*>(out + base + c) = o;
}

// xq[b,t,:] = hs[b,t+63,:] if t<=960 else 0 ; f32 in -> bf16 out
__global__ __launch_bounds__(256) void xq_k(const float* __restrict__ hs,
                                            u16* __restrict__ xq) {
  const int i = blockIdx.x * 256 + threadIdx.x;  // float4-group index
  const int row = i >> 8;
  const int t = row & (SEQ - 1);
  float4 v = make_float4(0.f, 0.f, 0.f, 0.f);
  if (t < SEQ - 63) v = reinterpret_cast<const float4*>(hs)[i + 63 * 256];
  ushort4 o = {f2b(v.x), f2b(v.y), f2b(v.z), f2b(v.w)};
  reinterpret_cast<ushort4*>(xq)[i] = o;
}

// rotary on q_c (bf16, in-place): only row 0 of each chunk, freqs = qpe[63]
__global__ __launch_bounds__(256) void rotq_k(u16* __restrict__ q,
                                              const float* __restrict__ qpe) {
  __shared__ float rb[DM];
  const size_t base = (size_t)blockIdx.x * 64 * DM;
  const int e = threadIdx.x << 2;
  ushort4 u = *reinterpret_cast<const ushort4*>(q + base + e);
  rb[e + 0] = u2f(u.x); rb[e + 1] = u2f(u.y); rb[e + 2] = u2f(u.z); rb[e + 3] = u2f(u.w);
  __syncthreads();
  u16 ov[4];
#pragma unroll
  for (int k = 0; k < 4; ++k) {
    const int ee = e + k;
    const int cc = ee & 63;
    const float f = qpe[63 * 64 + cc];
    const float t1 = rb[ee];
    const float part = (cc < 32) ? -rb[ee + 32] : rb[ee - 32];
    ov[k] = f2b(t1 * cosf(f) + part * sinf(f));
  }
  ushort4 o = {ov[0], ov[1], ov[2], ov[3]};
  *reinterpret_cast<ushort4*>(q + base + e) = o;
}

// rotary on kk (bf16, in-place): row rr, freqs = k_pos_emb[(rr&255)&127]
__global__ __launch_bounds__(256) void rotk_k(u16* __restrict__ kkb,
                                              const float* __restrict__ kpe) {
  const int rr = blockIdx.x;
  const float* fr = kpe + (size_t)((rr & 255) & 127) * 64;
  __shared__ float rb[DM];
  const size_t base = (size_t)rr * DM;
  const int e = threadIdx.x << 2;
  ushort4 u = *reinterpret_cast<const ushort4*>(kkb + base + e);
  rb[e + 0] = u2f(u.x); rb[e + 1] = u2f(u.y); rb[e + 2] = u2f(u.z); rb[e + 3] = u2f(u.w);
  __syncthreads();
  u16 ov[4];
#pragma unroll
  for (int k = 0; k < 4; ++k) {
    const int ee = e + k;
    const int cc = ee & 63;
    const float f = fr[cc];
    const float t1 = rb[ee];
    const float part = (cc < 32) ? -rb[ee + 32] : rb[ee - 32];
    ov[k] = f2b(t1 * cosf(f) + part * sinf(f));
  }
  ushort4 o = {ov[0], ov[1], ov[2], ov[3]};
  *reinterpret_cast<ushort4*>(kkb + base + e) = o;
}

// ---------------------------------------------------------------------------
// causal self-attention (bf16 q,k,v,o; f32 math), 64x64 tiles, online softmax
// ---------------------------------------------------------------------------
__global__ __launch_bounds__(256) void attn_self_k(const u16* __restrict__ q,
                                                   const u16* __restrict__ k,
                                                   const u16* __restrict__ v,
                                                   u16* __restrict__ o) {
  const int qt = blockIdx.x, h = blockIdx.y, b = blockIdx.z;
  __shared__ float qsT[64][68];
  __shared__ float kps[64][68];
  __shared__ float vs[64][68];
  const int tid = threadIdx.x;
  const int tx = tid & 15, ty = tid >> 4;
  const size_t bhbase = (size_t)b * SEQ * DM + (size_t)h * DHD;

#pragma unroll
  for (int rp = 0; rp < 4; ++rp) {
    const int fi = tid + rp * 256;
    const int r = fi >> 4, c4 = (fi & 15) << 2;
    ushort4 qu = *reinterpret_cast<const ushort4*>(q + bhbase + (size_t)(qt * 64 + r) * DM + c4);
    qsT[c4 + 0][r] = u2f(qu.x);
    qsT[c4 + 1][r] = u2f(qu.y);
    qsT[c4 + 2][r] = u2f(qu.z);
    qsT[c4 + 3][r] = u2f(qu.w);
  }
  float mrun[4], lrun[4], accO[4][4];
#pragma unroll
  for (int i = 0; i < 4; ++i) {
    mrun[i] = -1e30f; lrun[i] = 0.f;
#pragma unroll
    for (int j = 0; j < 4; ++j) accO[i][j] = 0.f;
  }

  for (int kt = 0; kt <= qt; ++kt) {
    __syncthreads();
#pragma unroll
    for (int rp = 0; rp < 4; ++rp) {
      const int fi = tid + rp * 256;
      const int r = fi >> 4, c4 = (fi & 15) << 2;
      const size_t g = bhbase + (size_t)(kt * 64 + r) * DM + c4;
      ushort4 ku = *reinterpret_cast<const ushort4*>(k + g);
      kps[c4 + 0][r] = u2f(ku.x);
      kps[c4 + 1][r] = u2f(ku.y);
      kps[c4 + 2][r] = u2f(ku.z);
      kps[c4 + 3][r] = u2f(ku.w);
      ushort4 vu = *reinterpret_cast<const ushort4*>(v + g);
      float4 v4 = make_float4(u2f(vu.x), u2f(vu.y), u2f(vu.z), u2f(vu.w));
      *reinterpret_cast<float4*>(&vs[r][c4]) = v4;
    }
    __syncthreads();

    float s[4][4] = {{0.f, 0.f, 0.f, 0.f}};
#pragma unroll 8
    for (int c = 0; c < 64; ++c) {
      float4 a4 = *reinterpret_cast<const float4*>(&qsT[c][ty << 2]);
      float4 b4 = *reinterpret_cast<const float4*>(&kps[c][tx << 2]);
      float a[4] = {a4.x, a4.y, a4.z, a4.w};
      float bb[4] = {b4.x, b4.y, b4.z, b4.w};
#pragma unroll
      for (int i = 0; i < 4; ++i)
#pragma unroll
        for (int j = 0; j < 4; ++j) s[i][j] = fmaf(a[i], bb[j], s[i][j]);
    }
    if (kt == qt) {
#pragma unroll
      for (int i = 0; i < 4; ++i)
#pragma unroll
        for (int j = 0; j < 4; ++j)
          if (((tx << 2) + j) > ((ty << 2) + i)) s[i][j] = -1e30f;
    }
#pragma unroll
    for (int i = 0; i < 4; ++i) {
      float mt = fmaxf(fmaxf(s[i][0], s[i][1]), fmaxf(s[i][2], s[i][3]));
      mt = fmaxf(mt, __shfl_xor(mt, 1, 16));
      mt = fmaxf(mt, __shfl_xor(mt, 2, 16));
      mt = fmaxf(mt, __shfl_xor(mt, 4, 16));
      mt = fmaxf(mt, __shfl_xor(mt, 8, 16));
      const float nm = fmaxf(mrun[i], mt);
      const float f = __expf(mrun[i] - nm);
      mrun[i] = nm;
      float rs = 0.f;
#pragma unroll
      for (int j = 0; j < 4; ++j) {
        s[i][j] = __expf(s[i][j] - nm);
        rs += s[i][j];
      }
      rs += __shfl_xor(rs, 1, 16);
      rs += __shfl_xor(rs, 2, 16);
      rs += __shfl_xor(rs, 4, 16);
      rs += __shfl_xor(rs, 8, 16);
      lrun[i] = lrun[i] * f + rs;
#pragma unroll
      for (int j = 0; j < 4; ++j) accO[i][j] *= f;
    }
    __syncthreads();
#pragma unroll
    for (int i = 0; i < 4; ++i)
#pragma unroll
      for (int j = 0; j < 4; ++j) kps[(ty << 2) + i][(tx << 2) + j] = s[i][j];
    __syncthreads();
#pragma unroll 8
    for (int kx = 0; kx < 64; ++kx) {
      float4 v4 = *reinterpret_cast<const float4*>(&vs[kx][tx << 2]);
      const float p0 = kps[(ty << 2) + 0][kx];
      const float p1 = kps[(ty << 2) + 1][kx];
      const float p2 = kps[(ty << 2) + 2][kx];
      const float p3 = kps[(ty << 2) + 3][kx];
      accO[0][0] += p0 * v4.x; accO[0][1] += p0 * v4.y; accO[0][2] += p0 * v4.z; accO[0][3] += p0 * v4.w;
      accO[1][0] += p1 * v4.x; accO[1][1] += p1 * v4.y; accO[1][2] += p1 * v4.z; accO[1][3] += p1 * v4.w;
      accO[2][0] += p2 * v4.x; accO[2][1] += p2 * v4.y; accO[2][2] += p2 * v4.z; accO[2][3] += p2 * v4.w;
      accO[3][0] += p3 * v4.x; accO[3][1] += p3 * v4.y; accO[3][2] += p3 * v4.z; accO[3][3] += p3 * v4.w;
    }
  }
#pragma unroll
  for (int i = 0; i < 4; ++i) {
    const float inv = 1.f / lrun[i];
    ushort4 ou = {f2b(accO[i][0] * inv), f2b(accO[i][1] * inv),
                  f2b(accO[i][2] * inv), f2b(accO[i][3] * inv)};
    *reinterpret_cast<ushort4*>(o + bhbase + (size_t)(qt * 64 + (ty << 2) + i) * DM + (tx << 2)) = ou;
  }
}

// ---------------------------------------------------------------------------
// chunked cross-attention: 257 keys (null + 256), bf16 q/kk/vv/o, f32 null
// ---------------------------------------------------------------------------
__global__ __launch_bounds__(256) void attn_cca_k(
    const u16* __restrict__ q, const u16* __restrict__ kkb,
    const u16* __restrict__ vvb, const float* __restrict__ nullk,
    const float* __restrict__ nullv, u16* __restrict__ o) {
  const int h = blockIdx.y, bk = blockIdx.z;
  __shared__ float qsT[64][68];
  __shared__ float kps[64][68];
  __shared__ float vs[64][68];
  const int tid = threadIdx.x;
  const int tx = tid & 15, ty = tid >> 4;
  const size_t qbase = (size_t)bk * 64 * DM + (size_t)h * DHD;

#pragma unroll
  for (int rp = 0; rp < 4; ++rp) {
    const int fi = tid + rp * 256;
    const int r = fi >> 4, c4 = (fi & 15) << 2;
    ushort4 qu = *reinterpret_cast<const ushort4*>(q + qbase + (size_t)r * DM + c4);
    qsT[c4 + 0][r] = u2f(qu.x);
    qsT[c4 + 1][r] = u2f(qu.y);
    qsT[c4 + 2][r] = u2f(qu.z);
    qsT[c4 + 3][r] = u2f(qu.w);
  }
  float mrun[4], lrun[4], accO[4][4];
#pragma unroll
  for (int i = 0; i < 4; ++i) {
    mrun[i] = -1e30f; lrun[i] = 0.f;
#pragma unroll
    for (int j = 0; j < 4; ++j) accO[i][j] = 0.f;
  }

  for (int kt = 0; kt < 5; ++kt) {
    __syncthreads();
#pragma unroll
    for (int rp = 0; rp < 4; ++rp) {
      const int fi = tid + rp * 256;
      const int r = fi >> 4, c4 = (fi & 15) << 2;
      const int kj = kt * 64 + r;
      float4 kv = make_float4(0.f, 0.f, 0.f, 0.f);
      float4 v4 = make_float4(0.f, 0.f, 0.f, 0.f);
      if (kj < 257) {
        if (kj == 0) {
          kv = *reinterpret_cast<const float4*>(nullk + h * DHD + c4);
          v4 = *reinterpret_cast<const float4*>(nullv + h * DHD + c4);
        } else {
          const size_t g = ((size_t)bk * 256 + (kj - 1)) * DM + h * DHD + c4;
          ushort4 ku = *reinterpret_cast<const ushort4*>(kkb + g);
          ushort4 vu = *reinterpret_cast<const ushort4*>(vvb + g);
          kv = make_float4(u2f(ku.x), u2f(ku.y), u2f(ku.z), u2f(ku.w));
          v4 = make_float4(u2f(vu.x), u2f(vu.y), u2f(vu.z), u2f(vu.w));
        }
      }
      kps[c4 + 0][r] = kv.x;
      kps[c4 + 1][r] = kv.y;
      kps[c4 + 2][r] = kv.z;
      kps[c4 + 3][r] = kv.w;
      *reinterpret_cast<float4*>(&vs[r][c4]) = v4;
    }
    __syncthreads();

    float s[4][4] = {{0.f, 0.f, 0.f, 0.f}};
#pragma unroll 8
    for (int c = 0; c < 64; ++c) {
      float4 a4 = *reinterpret_cast<const float4*>(&qsT[c][ty << 2]);
      float4 b4 = *reinterpret_cast<const float4*>(&kps[c][tx << 2]);
      float a[4] = {a4.x, a4.y, a4.z, a4.w};
      float bb[4] = {b4.x, b4.y, b4.z, b4.w};
#pragma unroll
      for (int i = 0; i < 4; ++i)
#pragma unroll
        for (int j = 0; j < 4; ++j) s[i][j] = fmaf(a[i], bb[j], s[i][j]);
    }
    if (kt == 4) {
#pragma unroll
      for (int i = 0; i < 4; ++i)
#pragma unroll
        for (int j = 0; j < 4; ++j)
          if (((tx << 2) + j) >= 1) s[i][j] = -1e30f;
    }
#pragma unroll
    for (int i = 0; i < 4; ++i) {
      float mt = fmaxf(fmaxf(s[i][0], s[i][1]), fmaxf(s[i][2], s[i][3]));
      mt = fmaxf(mt, __shfl_xor(mt, 1, 16));
      mt = fmaxf(mt, __shfl_xor(mt, 2, 16));
      mt = fmaxf(mt, __shfl_xor(mt, 4, 16));
      mt = fmaxf(mt, __shfl_xor(mt, 8, 16));
      const float nm = fmaxf(mrun[i], mt);
      const float f = __expf(mrun[i] - nm);
      mrun[i] = nm;
      float rs = 0.f;
#pragma unroll
      for (int j = 0; j < 4; ++j) {
        s[i][j] = __expf(s[i][j] - nm);
        rs += s[i][j];
      }
      rs += __shfl_xor(rs, 1, 16);
      rs += __shfl_xor(rs, 2, 16);
      rs += __shfl_xor(rs, 4, 16);
      rs += __shfl_xor(rs, 8, 16);
      lrun[i] = lrun[i] * f + rs;
#pragma unroll
      for (int j = 0; j < 4; ++j) accO[i][j] *= f;
    }
    __syncthreads();
#pragma unroll
    for (int i = 0; i < 4; ++i)
#pragma unroll
      for (int j = 0; j < 4; ++j) kps[(ty << 2) + i][(tx << 2) + j] = s[i][j];
    __syncthreads();
#pragma unroll 8
    for (int kx = 0; kx < 64; ++kx) {
      float4 v4 = *reinterpret_cast<const float4*>(&vs[kx][tx << 2]);
      const float p0 = kps[(ty << 2) + 0][kx];
      const float p1 = kps[(ty << 2) + 1][kx];
      const float p2 = kps[(ty << 2) + 2][kx];
      const float p3 = kps[(ty << 2) + 3][kx];
      accO[0][0] += p0 * v4.x; accO[0][1] += p0 * v4.y; accO[0][2] += p0 * v4.z; accO[0][3] += p0 * v4.w;
      accO[1][0] += p1 * v4.x; accO[1][1] += p1 * v4.y; accO[1][2] += p1 * v4.z; accO[1][3] += p1 * v4.w;
      accO[2][0] += p2 * v4.x; accO[2][1] += p2 * v4.y; accO[2][2] += p2 * v4.z; accO[2][3] += p2 * v4.w;
      accO[3][0] += p3 * v4.x; accO[3][1] += p3 * v4.y; accO[3][2] += p3 * v4.z; accO[3][3] += p3 * v4.w;
    }
  }
#pragma unroll
  for (int i = 0; i < 4; ++i) {
    const float inv = 1.f / lrun[i];
    ushort4 ou = {f2b(accO[i][0] * inv), f2b(accO[i][1] * inv),
                  f2b(accO[i][2] * inv), f2b(accO[i][3] * inv)};
    *reinterpret_cast<ushort4*>(o + qbase + (size_t)((ty << 2) + i) * DM + (tx << 2)) = ou;
  }
}

// ---------------------------------------------------------------------------
extern "C" void kernel_launch(void* const* d_in, const int* in_sizes, int n_in,
                              void* d_out, int out_size, void* d_ws, size_t ws_size,
                              hipStream_t stream) {
  const float* hidden    = (const float*)d_in[0];
  const float* retrieval = (const float*)d_in[1];
  const float* q_pos     = (const float*)d_in[2];
  const float* k_pos     = (const float*)d_in[3];
  const float* ln1_g     = (const float*)d_in[4];
  const float* ln1_b     = (const float*)d_in[5];
  const float* Wq_s      = (const float*)d_in[6];
  const float* Wk_s      = (const float*)d_in[7];
  const float* Wv_s      = (const float*)d_in[8];
  const float* Wo_s      = (const float*)d_in[9];
  const float* bo_s      = (const float*)d_in[10];
  const float* ln2_g     = (const float*)d_in[11];
  const float* ln2_b     = (const float*)d_in[12];
  const float* Wq_c      = (const float*)d_in[13];
  const float* Wk_c      = (const float*)d_in[14];
  const float* Wv_c      = (const float*)d_in[15];
  const float* Wo_c      = (const float*)d_in[16];
  const float* bo_c      = (const float*)d_in[17];
  const float* null_k    = (const float*)d_in[18];
  const float* null_v    = (const float*)d_in[19];
  const float* post_w    = (const float*)d_in[20];
  const float* W1        = (const float*)d_in[21];
  const float* b1        = (const float*)d_in[22];
  const float* W2        = (const float*)d_in[23];
  const float* b2        = (const float*)d_in[24];
  float* out = (float*)d_out;

  constexpr size_t MB = 1024 * 1024;
  char* W = (char*)d_ws;
  // weights arena: 8 x 2MB (1024x1024 bf16, [N,K])
  u16* Wt_qs = (u16*)(W + 0 * MB);
  u16* Wt_ks = (u16*)(W + 2 * MB);
  u16* Wt_vs = (u16*)(W + 4 * MB);
  u16* Wt_os = (u16*)(W + 6 * MB);
  u16* Wt_qc = (u16*)(W + 8 * MB);
  u16* Wt_kc = (u16*)(W + 10 * MB);
  u16* Wt_vc = (u16*)(W + 12 * MB);
  u16* Wt_oc = (u16*)(W + 14 * MB);
  float* s0 = (float*)(W + 16 * MB);   // 16MB f32
  float* s5 = (float*)(W + 32 * MB);   // 16MB f32 (hs)
  u16* qb    = (u16*)(W + 48 * MB);    // 8MB units
  u16* xqb   = (u16*)(W + 56 * MB);
  u16* kb    = (u16*)(W + 64 * MB);
  u16* vb    = (u16*)(W + 72 * MB);
  u16* attnb = (u16*)(W + 80 * MB);
  u16* xb    = (u16*)(W + 88 * MB);
  u16* retb  = kb;                     // 32MB span kb..xb (dead by then)
  u16* kkb   = (u16*)(W + 96 * MB);    // 32MB
  u16* vvb   = (u16*)(W + 128 * MB);   // 32MB
  u16* ff1b  = kkb;                    // alias (kk dead after cca)
  u16* W1t   = vvb;                    // [4096][1024] bf16 = 8MB (vv dead)
  u16* W2t   = vvb + 4u * 1024 * 1024; // [1024][4096] bf16 = 8MB
  u16* qcb   = qb;                     // q_c reuses q slot
  u16* ccab  = xb;                     // cca attn out
  u16* ccapb = attnb;                  // cca proj out
  u16* t5b   = xqb;                    // t5 out

  const dim3 blk(256);

  // --- weight transposes (small) ---
  wtrans_k<<<dim3(32, 32), blk, 0, stream>>>(Wq_s, Wt_qs, 1024, 1024);
  wtrans_k<<<dim3(32, 32), blk, 0, stream>>>(Wk_s, Wt_ks, 1024, 1024);
  wtrans_k<<<dim3(32, 32), blk, 0, stream>>>(Wv_s, Wt_vs, 1024, 1024);
  wtrans_k<<<dim3(32, 32), blk, 0, stream>>>(Wo_s, Wt_os, 1024, 1024);
  wtrans_k<<<dim3(32, 32), blk, 0, stream>>>(Wq_c, Wt_qc, 1024, 1024);
  wtrans_k<<<dim3(32, 32), blk, 0, stream>>>(Wk_c, Wt_kc, 1024, 1024);
  wtrans_k<<<dim3(32, 32), blk, 0, stream>>>(Wv_c, Wt_vc, 1024, 1024);
  wtrans_k<<<dim3(32, 32), blk, 0, stream>>>(Wo_c, Wt_oc, 1024, 1024);

  // --- self-attention path ---
  ln_k<true><<<dim3(4096), blk, 0, stream>>>(hidden, ln1_g, ln1_b, xb);
  mgemm_k<1, false, false, false><<<dim3(8, 32), blk, 0, stream>>>(
      xb, Wt_qs, qb, 4096, 1024, 1024, 0.125f, nullptr, nullptr);
  mgemm_k<1, false, false, false><<<dim3(8, 32), blk, 0, stream>>>(
      xb, Wt_ks, kb, 4096, 1024, 1024, 1.f, nullptr, nullptr);
  mgemm_k<1, false, false, false><<<dim3(8, 32), blk, 0, stream>>>(
      xb, Wt_vs, vb, 4096, 1024, 1024, 1.f, nullptr, nullptr);
  attn_self_k<<<dim3(16, 16, 4), blk, 0, stream>>>(qb, kb, vb, attnb);
  mgemm_k<0, true, true, false><<<dim3(8, 32), blk, 0, stream>>>(
      attnb, Wt_os, s0, 4096, 1024, 1024, 1.f, bo_s, hidden);
  ln_k<false><<<dim3(4096), blk, 0, stream>>>(s0, ln2_g, ln2_b, s5);

  // --- cross-attention path ---
  xq_k<<<dim3(4096), blk, 0, stream>>>(s5, xqb);
  mgemm_k<1, false, false, false><<<dim3(8, 32), blk, 0, stream>>>(
      xqb, Wt_qc, qcb, 4096, 1024, 1024, 0.125f, nullptr, nullptr);
  rotq_k<<<dim3(64), blk, 0, stream>>>(qcb, q_pos);
  cast_k<<<dim3(16384), blk, 0, stream>>>(retrieval, retb);
  mgemm_k<1, false, false, false><<<dim3(8, 128), blk, 0, stream>>>(
      retb, Wt_kc, kkb, 16384, 1024, 1024, 1.f, nullptr, nullptr);
  rotk_k<<<dim3(16384), blk, 0, stream>>>(kkb, k_pos);
  mgemm_k<1, false, false, false><<<dim3(8, 128), blk, 0, stream>>>(
      retb, Wt_vc, vvb, 16384, 1024, 1024, 1.f, nullptr, nullptr);
  attn_cca_k<<<dim3(1, 16, 64), blk, 0, stream>>>(qcb, kkb, vvb, null_k, null_v, ccab);

  // --- late weight transposes into dead vv region ---
  wtrans_k<<<dim3(128, 32), blk, 0, stream>>>(W1, W1t, 1024, 4096);
  wtrans_k<<<dim3(32, 128), blk, 0, stream>>>(W2, W2t, 4096, 1024);

  mgemm_k<1, true, false, false><<<dim3(8, 32), blk, 0, stream>>>(
      ccab, Wt_oc, ccapb, 4096, 1024, 1024, 1.f, bo_c, nullptr);
  t5_k<<<dim3(4096), blk, 0, stream>>>(ccapb, s5, post_w, t5b);

  // --- FFN ---
  mgemm_k<1, true, false, true><<<dim3(32, 32), blk, 0, stream>>>(
      t5b, W1t, ff1b, 4096, 4096, 1024, 1.f, b1, nullptr);
  mgemm_k<0, true, true, false><<<dim3(8, 32), blk, 0, stream>>>(
      ff1b, W2t, out, 4096, 1024, 4096, 1.f, b2, s5);
}

// Round 3
// 650.800 us; speedup vs baseline: 4.6147x; 1.4560x over previous
//
#include <hip/hip_runtime.h>
#include <hip/hip_bf16.h>
#include <math.h>

using u16 = unsigned short;

static constexpr int SEQ = 1024;
static constexpr int DM  = 1024;
static constexpr int DHD = 64;

typedef __bf16 bfv8 __attribute__((ext_vector_type(8)));
typedef float  f32x4 __attribute__((ext_vector_type(4)));

__device__ __forceinline__ float u2f(u16 u) {
  return __uint_as_float(((unsigned int)u) << 16);
}
__device__ __forceinline__ u16 f2b(float x) {
  __hip_bfloat16 h = __float2bfloat16(x);
  return *reinterpret_cast<u16*>(&h);
}
__device__ __forceinline__ void gload16(const u16* g, u16* l) {
  __builtin_amdgcn_global_load_lds(
      (const __attribute__((address_space(1))) unsigned int*)g,
      (__attribute__((address_space(3))) unsigned int*)l, 16, 0, 0);
}

// ---------------------------------------------------------------------------
// MFMA bf16 GEMM: C[M,N] = alpha*A[M,K]@Bt[N,K]^T (+bias)(+gelu)(+res)
// 128x128 tile, BK=64, 4 waves, 16x16x32 MFMA, global_load_lds staging (m97)
// ---------------------------------------------------------------------------
template <int OT /*0=f32,1=bf16*/, bool HASBIAS, bool HASRES, bool DOGELU>
__global__ __launch_bounds__(256) void mgemm_k(
    const u16* __restrict__ A, const u16* __restrict__ Bt, void* __restrict__ C,
    int M, int N, int K, float alpha,
    const float* __restrict__ bias, const float* __restrict__ res) {
  __shared__ u16 As[128 * 64];
  __shared__ u16 Bs[128 * 64];
  const int tid = threadIdx.x;
  const int w = tid >> 6, lane = tid & 63;
  const int wr = w >> 1, wc = w & 1;
  const int row0 = blockIdx.y << 7, col0 = blockIdx.x << 7;
  f32x4 acc[4][4] = {};

  const int c0 = (w << 2) * 64 + lane;  // base chunk id for issue i=0
  for (int k0 = 0; k0 < K; k0 += 64) {
#pragma unroll
    for (int i = 0; i < 4; ++i) {
      const int c = c0 + (i << 6);
      const int r = c >> 3, cb = (c & 7) << 3;
      gload16(A + (size_t)(row0 + r) * K + k0 + cb, &As[((w << 2) + i) << 9]);
      gload16(Bt + (size_t)(col0 + r) * K + k0 + cb, &Bs[((w << 2) + i) << 9]);
    }
    __syncthreads();
#pragma unroll
    for (int kk = 0; kk < 2; ++kk) {
      bfv8 af[4], bfr[4];
#pragma unroll
      for (int m = 0; m < 4; ++m)
        af[m] = *reinterpret_cast<const bfv8*>(
            &As[((wr << 6) + (m << 4) + (lane & 15)) * 64 + (kk << 5) + ((lane >> 4) << 3)]);
#pragma unroll
      for (int n = 0; n < 4; ++n)
        bfr[n] = *reinterpret_cast<const bfv8*>(
            &Bs[((wc << 6) + (n << 4) + (lane & 15)) * 64 + (kk << 5) + ((lane >> 4) << 3)]);
#pragma unroll
      for (int m = 0; m < 4; ++m)
#pragma unroll
        for (int n = 0; n < 4; ++n)
          acc[m][n] = __builtin_amdgcn_mfma_f32_16x16x32_bf16(af[m], bfr[n], acc[m][n], 0, 0, 0);
    }
    __syncthreads();
  }

  const int lr = (lane >> 4) << 2;
  const int lc = lane & 15;
#pragma unroll
  for (int m = 0; m < 4; ++m) {
#pragma unroll
    for (int n = 0; n < 4; ++n) {
#pragma unroll
      for (int r = 0; r < 4; ++r) {
        const int gr = row0 + (wr << 6) + (m << 4) + lr + r;
        const int gc = col0 + (wc << 6) + (n << 4) + lc;
        float v = acc[m][n][r] * alpha;
        if constexpr (HASBIAS) v += bias[gc];
        if constexpr (DOGELU) {
          const float x = v;
          v = 0.5f * x * (1.f + tanhf(0.7978845608f * (x + 0.044715f * x * x * x)));
        }
        if constexpr (HASRES) v += res[(size_t)gr * N + gc];
        if constexpr (OT == 0)
          ((float*)C)[(size_t)gr * N + gc] = v;
        else
          ((u16*)C)[(size_t)gr * N + gc] = f2b(v);
      }
    }
  }
}

// ---------------------------------------------------------------------------
// weight transpose+cast: in f32 [K,N] -> out bf16 [N,K]
// ---------------------------------------------------------------------------
__global__ __launch_bounds__(256) void wtrans_k(const float* __restrict__ in,
                                                u16* __restrict__ out, int K, int N) {
  __shared__ float t[32][33];
  const int tx = threadIdx.x & 31, ty = threadIdx.x >> 5;
  const int r0 = blockIdx.y << 5, c0 = blockIdx.x << 5;
#pragma unroll
  for (int i = 0; i < 4; ++i)
    t[ty + 8 * i][tx] = in[(size_t)(r0 + ty + 8 * i) * N + c0 + tx];
  __syncthreads();
#pragma unroll
  for (int i = 0; i < 4; ++i)
    out[(size_t)(c0 + ty + 8 * i) * K + r0 + tx] = f2b(t[tx][ty + 8 * i]);
}

// flat f32 -> bf16 cast (one float4 per thread)
__global__ __launch_bounds__(256) void cast_k(const float* __restrict__ in,
                                              u16* __restrict__ out) {
  const int i = blockIdx.x * 256 + threadIdx.x;
  float4 v = reinterpret_cast<const float4*>(in)[i];
  ushort4 o = {f2b(v.x), f2b(v.y), f2b(v.z), f2b(v.w)};
  reinterpret_cast<ushort4*>(out)[i] = o;
}

// ---------------------------------------------------------------------------
// LayerNorm rows of 1024; f32 in, f32 or bf16 out
// ---------------------------------------------------------------------------
template <bool BF16OUT>
__global__ __launch_bounds__(256) void ln_k(const float* __restrict__ in,
                                            const float* __restrict__ g,
                                            const float* __restrict__ b,
                                            void* __restrict__ out) {
  const int tid = threadIdx.x;
  const int c = tid << 2;
  const size_t base = (size_t)blockIdx.x * DM;
  float4 x = *reinterpret_cast<const float4*>(in + base + c);
  float s = x.x + x.y + x.z + x.w;
  float ss = x.x * x.x + x.y * x.y + x.z * x.z + x.w * x.w;
#pragma unroll
  for (int m = 1; m < 64; m <<= 1) {
    s += __shfl_xor(s, m, 64);
    ss += __shfl_xor(ss, m, 64);
  }
  __shared__ float ls[4], lss[4];
  if ((tid & 63) == 0) { ls[tid >> 6] = s; lss[tid >> 6] = ss; }
  __syncthreads();
  s = (ls[0] + ls[1]) + (ls[2] + ls[3]);
  ss = (lss[0] + lss[1]) + (lss[2] + lss[3]);
  const float mu = s * (1.f / DM);
  const float var = ss * (1.f / DM) - mu * mu;
  const float rstd = rsqrtf(var + 1e-5f);
  float4 g4 = *reinterpret_cast<const float4*>(g + c);
  float4 b4 = *reinterpret_cast<const float4*>(b + c);
  float4 o;
  o.x = (x.x - mu) * rstd * g4.x + b4.x;
  o.y = (x.y - mu) * rstd * g4.y + b4.y;
  o.z = (x.z - mu) * rstd * g4.z + b4.z;
  o.w = (x.w - mu) * rstd * g4.w + b4.w;
  if constexpr (BF16OUT) {
    ushort4 u = {f2b(o.x), f2b(o.y), f2b(o.z), f2b(o.w)};
    *reinterpret_cast<ushort4*>((u16*)out + base + c) = u;
  } else {
    *reinterpret_cast<float4*>((float*)out + base + c) = o;
  }
}

// ---------------------------------------------------------------------------
// t5norm(shift_right_63(cca_bf16) + hs_f32) * w -> bf16
// ---------------------------------------------------------------------------
__global__ __launch_bounds__(256) void t5_k(const u16* __restrict__ cca,
                                            const float* __restrict__ hs,
                                            const float* __restrict__ w,
                                            u16* __restrict__ out) {
  const int tid = threadIdx.x;
  const int row = blockIdx.x;
  const int t = row & (SEQ - 1);
  const int c = tid << 2;
  const size_t base = (size_t)row * DM;
  float4 x = *reinterpret_cast<const float4*>(hs + base + c);
  if (t >= 63) {
    ushort4 cu = *reinterpret_cast<const ushort4*>(cca + base - (size_t)63 * DM + c);
    x.x += u2f(cu.x); x.y += u2f(cu.y); x.z += u2f(cu.z); x.w += u2f(cu.w);
  }
  float ss = x.x * x.x + x.y * x.y + x.z * x.z + x.w * x.w;
#pragma unroll
  for (int m = 1; m < 64; m <<= 1) ss += __shfl_xor(ss, m, 64);
  __shared__ float lss[4];
  if ((tid & 63) == 0) lss[tid >> 6] = ss;
  __syncthreads();
  ss = (lss[0] + lss[1]) + (lss[2] + lss[3]);
  const float rms = sqrtf(ss * (1.f / DM));
  const float inv = 1.f / fmaxf(rms, 1e-6f);
  float4 w4 = *reinterpret_cast<const float4*>(w + c);
  ushort4 o = {f2b(x.x * inv * w4.x), f2b(x.y * inv * w4.y),
               f2b(x.z * inv * w4.z), f2b(x.w * inv * w4.w)};
  *reinterpret_cast<ushort4*>(out + base + c) = o;
}

// xq[b,t,:] = hs[b,t+63,:] if t<=960 else 0 ; f32 in -> bf16 out
__global__ __launch_bounds__(256) void xq_k(const float* __restrict__ hs,
                                            u16* __restrict__ xq) {
  const int i = blockIdx.x * 256 + threadIdx.x;  // float4-group index
  const int row = i >> 8;
  const int t = row & (SEQ - 1);
  float4 v = make_float4(0.f, 0.f, 0.f, 0.f);
  if (t < SEQ - 63) v = reinterpret_cast<const float4*>(hs)[i + 63 * 256];
  ushort4 o = {f2b(v.x), f2b(v.y), f2b(v.z), f2b(v.w)};
  reinterpret_cast<ushort4*>(xq)[i] = o;
}

// rotary on q_c (bf16, in-place): only row 0 of each chunk, freqs = qpe[63]
__global__ __launch_bounds__(256) void rotq_k(u16* __restrict__ q,
                                              const float* __restrict__ qpe) {
  __shared__ float rb[DM];
  const size_t base = (size_t)blockIdx.x * 64 * DM;
  const int e = threadIdx.x << 2;
  ushort4 u = *reinterpret_cast<const ushort4*>(q + base + e);
  rb[e + 0] = u2f(u.x); rb[e + 1] = u2f(u.y); rb[e + 2] = u2f(u.z); rb[e + 3] = u2f(u.w);
  __syncthreads();
  u16 ov[4];
#pragma unroll
  for (int k = 0; k < 4; ++k) {
    const int ee = e + k;
    const int cc = ee & 63;
    const float f = qpe[63 * 64 + cc];
    const float t1 = rb[ee];
    const float part = (cc < 32) ? -rb[ee + 32] : rb[ee - 32];
    ov[k] = f2b(t1 * cosf(f) + part * sinf(f));
  }
  ushort4 o = {ov[0], ov[1], ov[2], ov[3]};
  *reinterpret_cast<ushort4*>(q + base + e) = o;
}

// rotary on kk (bf16, in-place): row rr, freqs = k_pos_emb[(rr&255)&127]
__global__ __launch_bounds__(256) void rotk_k(u16* __restrict__ kkb,
                                              const float* __restrict__ kpe) {
  const int rr = blockIdx.x;
  const float* fr = kpe + (size_t)((rr & 255) & 127) * 64;
  __shared__ float rb[DM];
  const size_t base = (size_t)rr * DM;
  const int e = threadIdx.x << 2;
  ushort4 u = *reinterpret_cast<const ushort4*>(kkb + base + e);
  rb[e + 0] = u2f(u.x); rb[e + 1] = u2f(u.y); rb[e + 2] = u2f(u.z); rb[e + 3] = u2f(u.w);
  __syncthreads();
  u16 ov[4];
#pragma unroll
  for (int k = 0; k < 4; ++k) {
    const int ee = e + k;
    const int cc = ee & 63;
    const float f = fr[cc];
    const float t1 = rb[ee];
    const float part = (cc < 32) ? -rb[ee + 32] : rb[ee - 32];
    ov[k] = f2b(t1 * cosf(f) + part * sinf(f));
  }
  ushort4 o = {ov[0], ov[1], ov[2], ov[3]};
  *reinterpret_cast<ushort4*>(kkb + base + e) = o;
}

// ---------------------------------------------------------------------------
// MFMA causal self-attention. Block = (qt, h, b), 4 waves; wave w owns q rows
// [w*16, w*16+16). Per 64-key tile: QK^T (8 mfma), online softmax in regs,
// P via per-wave LDS strip, PV (8 mfma) vs LDS-transposed V.
// LDS rows padded to 88 u16 = 176B: 16B-aligned ds_read_b128, 44 dw/row ->
// 12-bank rotation/row -> conflict-free fragment reads.
// ---------------------------------------------------------------------------
__global__ __launch_bounds__(256) void attn_self_k(const u16* __restrict__ q,
                                                   const u16* __restrict__ k,
                                                   const u16* __restrict__ v,
                                                   u16* __restrict__ o) {
  const int qt = blockIdx.x, h = blockIdx.y, b = blockIdx.z;
  __shared__ u16 qs[64][88];
  __shared__ u16 ks[64][88];
  __shared__ u16 vt[64][88];   // V transposed: [d][key]
  __shared__ u16 ps[64][88];   // P: [q][key], per-wave strips
  const int tid = threadIdx.x;
  const int w = tid >> 6, lane = tid & 63;
  const int strip = w << 4;
  const int lrow = lane & 15, lk = lane >> 4;
  const size_t bhbase = (size_t)b * SEQ * DM + (size_t)h * DHD;

#pragma unroll
  for (int rp = 0; rp < 4; ++rp) {
    const int fi = tid + (rp << 8);
    const int r = fi >> 4, c4 = (fi & 15) << 2;
    *reinterpret_cast<ushort4*>(&qs[r][c4]) =
        *reinterpret_cast<const ushort4*>(q + bhbase + (size_t)(qt * 64 + r) * DM + c4);
  }

  float mrun[4], lrun[4];
  f32x4 accO[4] = {};
#pragma unroll
  for (int r = 0; r < 4; ++r) { mrun[r] = -1e30f; lrun[r] = 0.f; }

  for (int kt = 0; kt <= qt; ++kt) {
    __syncthreads();
#pragma unroll
    for (int rp = 0; rp < 4; ++rp) {
      const int fi = tid + (rp << 8);
      const int r = fi >> 4, c4 = (fi & 15) << 2;
      const size_t g = bhbase + (size_t)(kt * 64 + r) * DM + c4;
      *reinterpret_cast<ushort4*>(&ks[r][c4]) = *reinterpret_cast<const ushort4*>(k + g);
      ushort4 vu = *reinterpret_cast<const ushort4*>(v + g);
      vt[c4 + 0][r] = vu.x; vt[c4 + 1][r] = vu.y;
      vt[c4 + 2][r] = vu.z; vt[c4 + 3][r] = vu.w;
    }
    __syncthreads();

    // QK^T
    f32x4 sacc[4] = {};
#pragma unroll
    for (int kk = 0; kk < 2; ++kk) {
      bfv8 qf = *reinterpret_cast<const bfv8*>(&qs[strip + lrow][(kk << 5) + (lk << 3)]);
#pragma unroll
      for (int n = 0; n < 4; ++n) {
        bfv8 kf = *reinterpret_cast<const bfv8*>(&ks[(n << 4) + lrow][(kk << 5) + (lk << 3)]);
        sacc[n] = __builtin_amdgcn_mfma_f32_16x16x32_bf16(qf, kf, sacc[n], 0, 0, 0);
      }
    }
    if (kt == qt) {
#pragma unroll
      for (int n = 0; n < 4; ++n)
#pragma unroll
        for (int r = 0; r < 4; ++r)
          if ((n << 4) + lrow > strip + (lk << 2) + r) sacc[n][r] = -1e30f;
    }
    // online softmax (rows (lk<<2)+r of strip; cols across 16-lane group)
#pragma unroll
    for (int r = 0; r < 4; ++r) {
      float mt = fmaxf(fmaxf(sacc[0][r], sacc[1][r]), fmaxf(sacc[2][r], sacc[3][r]));
      mt = fmaxf(mt, __shfl_xor(mt, 1));
      mt = fmaxf(mt, __shfl_xor(mt, 2));
      mt = fmaxf(mt, __shfl_xor(mt, 4));
      mt = fmaxf(mt, __shfl_xor(mt, 8));
      const float nm = fmaxf(mrun[r], mt);
      const float f = __expf(mrun[r] - nm);
      mrun[r] = nm;
      float p0 = __expf(sacc[0][r] - nm);
      float p1 = __expf(sacc[1][r] - nm);
      float p2 = __expf(sacc[2][r] - nm);
      float p3 = __expf(sacc[3][r] - nm);
      float rs = (p0 + p1) + (p2 + p3);
      rs += __shfl_xor(rs, 1);
      rs += __shfl_xor(rs, 2);
      rs += __shfl_xor(rs, 4);
      rs += __shfl_xor(rs, 8);
      lrun[r] = lrun[r] * f + rs;
#pragma unroll
      for (int nd = 0; nd < 4; ++nd) accO[nd][r] *= f;
      const int prow = strip + (lk << 2) + r;
      ps[prow][lrow +  0] = f2b(p0);
      ps[prow][lrow + 16] = f2b(p1);
      ps[prow][lrow + 32] = f2b(p2);
      ps[prow][lrow + 48] = f2b(p3);
    }
    // PV (reads own strip of ps; compiler inserts lgkmcnt for in-wave order)
#pragma unroll
    for (int kk = 0; kk < 2; ++kk) {
      bfv8 pf = *reinterpret_cast<const bfv8*>(&ps[strip + lrow][(kk << 5) + (lk << 3)]);
#pragma unroll
      for (int nd = 0; nd < 4; ++nd) {
        bfv8 vf = *reinterpret_cast<const bfv8*>(&vt[(nd << 4) + lrow][(kk << 5) + (lk << 3)]);
        accO[nd] = __builtin_amdgcn_mfma_f32_16x16x32_bf16(pf, vf, accO[nd], 0, 0, 0);
      }
    }
  }
#pragma unroll
  for (int r = 0; r < 4; ++r) {
    const float inv = 1.f / lrun[r];
    const size_t rowoff = bhbase + (size_t)(qt * 64 + strip + (lk << 2) + r) * DM;
#pragma unroll
    for (int nd = 0; nd < 4; ++nd)
      o[rowoff + (nd << 4) + lrow] = f2b(accO[nd][r] * inv);
  }
}

// ---------------------------------------------------------------------------
// MFMA chunked cross-attention: 257 keys (null + 256 retrieved), no causal.
// Block = (1, h, bk), 4 waves. Tiles kt=0..4; tile 4 has only key 256 valid.
// ---------------------------------------------------------------------------
__global__ __launch_bounds__(256) void attn_cca_k(
    const u16* __restrict__ q, const u16* __restrict__ kkb,
    const u16* __restrict__ vvb, const float* __restrict__ nullk,
    const float* __restrict__ nullv, u16* __restrict__ o) {
  const int h = blockIdx.y, bk = blockIdx.z;
  __shared__ u16 qs[64][88];
  __shared__ u16 ks[64][88];
  __shared__ u16 vt[64][88];
  __shared__ u16 ps[64][88];
  const int tid = threadIdx.x;
  const int w = tid >> 6, lane = tid & 63;
  const int strip = w << 4;
  const int lrow = lane & 15, lk = lane >> 4;
  const size_t qbase = (size_t)bk * 64 * DM + (size_t)h * DHD;

#pragma unroll
  for (int rp = 0; rp < 4; ++rp) {
    const int fi = tid + (rp << 8);
    const int r = fi >> 4, c4 = (fi & 15) << 2;
    *reinterpret_cast<ushort4*>(&qs[r][c4]) =
        *reinterpret_cast<const ushort4*>(q + qbase + (size_t)r * DM + c4);
  }

  float mrun[4], lrun[4];
  f32x4 accO[4] = {};
#pragma unroll
  for (int r = 0; r < 4; ++r) { mrun[r] = -1e30f; lrun[r] = 0.f; }

  for (int kt = 0; kt < 5; ++kt) {
    __syncthreads();
#pragma unroll
    for (int rp = 0; rp < 4; ++rp) {
      const int fi = tid + (rp << 8);
      const int r = fi >> 4, c4 = (fi & 15) << 2;
      const int kj = kt * 64 + r;
      ushort4 ku = {0, 0, 0, 0}, vu = {0, 0, 0, 0};
      if (kj == 0) {
        float4 nk4 = *reinterpret_cast<const float4*>(nullk + h * DHD + c4);
        float4 nv4 = *reinterpret_cast<const float4*>(nullv + h * DHD + c4);
        ku = {f2b(nk4.x), f2b(nk4.y), f2b(nk4.z), f2b(nk4.w)};
        vu = {f2b(nv4.x), f2b(nv4.y), f2b(nv4.z), f2b(nv4.w)};
      } else if (kj <= 256) {
        const size_t g = ((size_t)bk * 256 + (kj - 1)) * DM + h * DHD + c4;
        ku = *reinterpret_cast<const ushort4*>(kkb + g);
        vu = *reinterpret_cast<const ushort4*>(vvb + g);
      }
      *reinterpret_cast<ushort4*>(&ks[r][c4]) = ku;
      vt[c4 + 0][r] = vu.x; vt[c4 + 1][r] = vu.y;
      vt[c4 + 2][r] = vu.z; vt[c4 + 3][r] = vu.w;
    }
    __syncthreads();

    f32x4 sacc[4] = {};
#pragma unroll
    for (int kk = 0; kk < 2; ++kk) {
      bfv8 qf = *reinterpret_cast<const bfv8*>(&qs[strip + lrow][(kk << 5) + (lk << 3)]);
#pragma unroll
      for (int n = 0; n < 4; ++n) {
        bfv8 kf = *reinterpret_cast<const bfv8*>(&ks[(n << 4) + lrow][(kk << 5) + (lk << 3)]);
        sacc[n] = __builtin_amdgcn_mfma_f32_16x16x32_bf16(qf, kf, sacc[n], 0, 0, 0);
      }
    }
    if (kt == 4) {  // only key 256 (local col 0) valid
#pragma unroll
      for (int n = 0; n < 4; ++n)
#pragma unroll
        for (int r = 0; r < 4; ++r)
          if ((n << 4) + lrow >= 1) sacc[n][r] = -1e30f;
    }
#pragma unroll
    for (int r = 0; r < 4; ++r) {
      float mt = fmaxf(fmaxf(sacc[0][r], sacc[1][r]), fmaxf(sacc[2][r], sacc[3][r]));
      mt = fmaxf(mt, __shfl_xor(mt, 1));
      mt = fmaxf(mt, __shfl_xor(mt, 2));
      mt = fmaxf(mt, __shfl_xor(mt, 4));
      mt = fmaxf(mt, __shfl_xor(mt, 8));
      const float nm = fmaxf(mrun[r], mt);
      const float f = __expf(mrun[r] - nm);
      mrun[r] = nm;
      float p0 = __expf(sacc[0][r] - nm);
      float p1 = __expf(sacc[1][r] - nm);
      float p2 = __expf(sacc[2][r] - nm);
      float p3 = __expf(sacc[3][r] - nm);
      float rs = (p0 + p1) + (p2 + p3);
      rs += __shfl_xor(rs, 1);
      rs += __shfl_xor(rs, 2);
      rs += __shfl_xor(rs, 4);
      rs += __shfl_xor(rs, 8);
      lrun[r] = lrun[r] * f + rs;
#pragma unroll
      for (int nd = 0; nd < 4; ++nd) accO[nd][r] *= f;
      const int prow = strip + (lk << 2) + r;
      ps[prow][lrow +  0] = f2b(p0);
      ps[prow][lrow + 16] = f2b(p1);
      ps[prow][lrow + 32] = f2b(p2);
      ps[prow][lrow + 48] = f2b(p3);
    }
#pragma unroll
    for (int kk = 0; kk < 2; ++kk) {
      bfv8 pf = *reinterpret_cast<const bfv8*>(&ps[strip + lrow][(kk << 5) + (lk << 3)]);
#pragma unroll
      for (int nd = 0; nd < 4; ++nd) {
        bfv8 vf = *reinterpret_cast<const bfv8*>(&vt[(nd << 4) + lrow][(kk << 5) + (lk << 3)]);
        accO[nd] = __builtin_amdgcn_mfma_f32_16x16x32_bf16(pf, vf, accO[nd], 0, 0, 0);
      }
    }
  }
#pragma unroll
  for (int r = 0; r < 4; ++r) {
    const float inv = 1.f / lrun[r];
    const size_t rowoff = qbase + (size_t)(strip + (lk << 2) + r) * DM;
#pragma unroll
    for (int nd = 0; nd < 4; ++nd)
      o[rowoff + (nd << 4) + lrow] = f2b(accO[nd][r] * inv);
  }
}

// ---------------------------------------------------------------------------
extern "C" void kernel_launch(void* const* d_in, const int* in_sizes, int n_in,
                              void* d_out, int out_size, void* d_ws, size_t ws_size,
                              hipStream_t stream) {
  const float* hidden    = (const float*)d_in[0];
  const float* retrieval = (const float*)d_in[1];
  const float* q_pos     = (const float*)d_in[2];
  const float* k_pos     = (const float*)d_in[3];
  const float* ln1_g     = (const float*)d_in[4];
  const float* ln1_b     = (const float*)d_in[5];
  const float* Wq_s      = (const float*)d_in[6];
  const float* Wk_s      = (const float*)d_in[7];
  const float* Wv_s      = (const float*)d_in[8];
  const float* Wo_s      = (const float*)d_in[9];
  const float* bo_s      = (const float*)d_in[10];
  const float* ln2_g     = (const float*)d_in[11];
  const float* ln2_b     = (const float*)d_in[12];
  const float* Wq_c      = (const float*)d_in[13];
  const float* Wk_c      = (const float*)d_in[14];
  const float* Wv_c      = (const float*)d_in[15];
  const float* Wo_c      = (const float*)d_in[16];
  const float* bo_c      = (const float*)d_in[17];
  const float* null_k    = (const float*)d_in[18];
  const float* null_v    = (const float*)d_in[19];
  const float* post_w    = (const float*)d_in[20];
  const float* W1        = (const float*)d_in[21];
  const float* b1        = (const float*)d_in[22];
  const float* W2        = (const float*)d_in[23];
  const float* b2        = (const float*)d_in[24];
  float* out = (float*)d_out;

  constexpr size_t MB = 1024 * 1024;
  char* W = (char*)d_ws;
  // weights arena: 8 x 2MB (1024x1024 bf16, [N,K])
  u16* Wt_qs = (u16*)(W + 0 * MB);
  u16* Wt_ks = (u16*)(W + 2 * MB);
  u16* Wt_vs = (u16*)(W + 4 * MB);
  u16* Wt_os = (u16*)(W + 6 * MB);
  u16* Wt_qc = (u16*)(W + 8 * MB);
  u16* Wt_kc = (u16*)(W + 10 * MB);
  u16* Wt_vc = (u16*)(W + 12 * MB);
  u16* Wt_oc = (u16*)(W + 14 * MB);
  float* s0 = (float*)(W + 16 * MB);   // 16MB f32
  float* s5 = (float*)(W + 32 * MB);   // 16MB f32 (hs)
  u16* qb    = (u16*)(W + 48 * MB);    // 8MB units
  u16* xqb   = (u16*)(W + 56 * MB);
  u16* kb    = (u16*)(W + 64 * MB);
  u16* vb    = (u16*)(W + 72 * MB);
  u16* attnb = (u16*)(W + 80 * MB);
  u16* xb    = (u16*)(W + 88 * MB);
  u16* retb  = kb;                     // 32MB span kb..xb (dead by then)
  u16* kkb   = (u16*)(W + 96 * MB);    // 32MB
  u16* vvb   = (u16*)(W + 128 * MB);   // 32MB
  u16* ff1b  = kkb;                    // alias (kk dead after cca)
  u16* W1t   = vvb;                    // [4096][1024] bf16 = 8MB (vv dead)
  u16* W2t   = vvb + 4u * 1024 * 1024; // [1024][4096] bf16 = 8MB
  u16* qcb   = qb;                     // q_c reuses q slot
  u16* ccab  = xb;                     // cca attn out
  u16* ccapb = attnb;                  // cca proj out
  u16* t5b   = xqb;                    // t5 out

  const dim3 blk(256);

  // --- weight transposes (small) ---
  wtrans_k<<<dim3(32, 32), blk, 0, stream>>>(Wq_s, Wt_qs, 1024, 1024);
  wtrans_k<<<dim3(32, 32), blk, 0, stream>>>(Wk_s, Wt_ks, 1024, 1024);
  wtrans_k<<<dim3(32, 32), blk, 0, stream>>>(Wv_s, Wt_vs, 1024, 1024);
  wtrans_k<<<dim3(32, 32), blk, 0, stream>>>(Wo_s, Wt_os, 1024, 1024);
  wtrans_k<<<dim3(32, 32), blk, 0, stream>>>(Wq_c, Wt_qc, 1024, 1024);
  wtrans_k<<<dim3(32, 32), blk, 0, stream>>>(Wk_c, Wt_kc, 1024, 1024);
  wtrans_k<<<dim3(32, 32), blk, 0, stream>>>(Wv_c, Wt_vc, 1024, 1024);
  wtrans_k<<<dim3(32, 32), blk, 0, stream>>>(Wo_c, Wt_oc, 1024, 1024);

  // --- self-attention path ---
  ln_k<true><<<dim3(4096), blk, 0, stream>>>(hidden, ln1_g, ln1_b, xb);
  mgemm_k<1, false, false, false><<<dim3(8, 32), blk, 0, stream>>>(
      xb, Wt_qs, qb, 4096, 1024, 1024, 0.125f, nullptr, nullptr);
  mgemm_k<1, false, false, false><<<dim3(8, 32), blk, 0, stream>>>(
      xb, Wt_ks, kb, 4096, 1024, 1024, 1.f, nullptr, nullptr);
  mgemm_k<1, false, false, false><<<dim3(8, 32), blk, 0, stream>>>(
      xb, Wt_vs, vb, 4096, 1024, 1024, 1.f, nullptr, nullptr);
  attn_self_k<<<dim3(16, 16, 4), blk, 0, stream>>>(qb, kb, vb, attnb);
  mgemm_k<0, true, true, false><<<dim3(8, 32), blk, 0, stream>>>(
      attnb, Wt_os, s0, 4096, 1024, 1024, 1.f, bo_s, hidden);
  ln_k<false><<<dim3(4096), blk, 0, stream>>>(s0, ln2_g, ln2_b, s5);

  // --- cross-attention path ---
  xq_k<<<dim3(4096), blk, 0, stream>>>(s5, xqb);
  mgemm_k<1, false, false, false><<<dim3(8, 32), blk, 0, stream>>>(
      xqb, Wt_qc, qcb, 4096, 1024, 1024, 0.125f, nullptr, nullptr);
  rotq_k<<<dim3(64), blk, 0, stream>>>(qcb, q_pos);
  cast_k<<<dim3(16384), blk, 0, stream>>>(retrieval, retb);
  mgemm_k<1, false, false, false><<<dim3(8, 128), blk, 0, stream>>>(
      retb, Wt_kc, kkb, 16384, 1024, 1024, 1.f, nullptr, nullptr);
  rotk_k<<<dim3(16384), blk, 0, stream>>>(kkb, k_pos);
  mgemm_k<1, false, false, false><<<dim3(8, 128), blk, 0, stream>>>(
      retb, Wt_vc, vvb, 16384, 1024, 1024, 1.f, nullptr, nullptr);
  attn_cca_k<<<dim3(1, 16, 64), blk, 0, stream>>>(qcb, kkb, vvb, null_k, null_v, ccab);

  // --- late weight transposes into dead vv region ---
  wtrans_k<<<dim3(128, 32), blk, 0, stream>>>(W1, W1t, 1024, 4096);
  wtrans_k<<<dim3(32, 128), blk, 0, stream>>>(W2, W2t, 4096, 1024);

  mgemm_k<1, true, false, false><<<dim3(8, 32), blk, 0, stream>>>(
      ccab, Wt_oc, ccapb, 4096, 1024, 1024, 1.f, bo_c, nullptr);
  t5_k<<<dim3(4096), blk, 0, stream>>>(ccapb, s5, post_w, t5b);

  // --- FFN ---
  mgemm_k<1, true, false, true><<<dim3(32, 32), blk, 0, stream>>>(
      t5b, W1t, ff1b, 4096, 4096, 1024, 1.f, b1, nullptr);
  mgemm_k<0, true, true, false><<<dim3(8, 32), blk, 0, stream>>>(
      ff1b, W2t, out, 4096, 1024, 4096, 1.f, b2, s5);
}